// Round 21
// baseline (449.341 us; speedup 1.0000x reference)
//
#include <hip/hip_runtime.h>
#include <cstddef>

constexpr int NODES = 100000;
constexpr int NPB   = 64;                      // nodes per scatter bin / region
constexpr int NBUCK = (NODES + NPB - 1) / NPB; // 1563
constexpr int RCAP  = 4096;                    // recs per region (mean ~3200 incl pads)
constexpr int SLOTS = 10;                      // LDS slots per bin (flush at 8)
constexpr int SGRID = 256;                     // scatter blocks (1/CU)
constexpr int GNPB  = 32;                      // nodes per gather block (half region)
constexpr int GCAP  = 1792;                    // gather lraw capacity (mean 1024 +24 sigma; 18KB -> 8 blocks/CU)
constexpr int FCAP  = 128;                     // flush-list capacity (<=64/round possible)

typedef unsigned int uint;
typedef unsigned short u16;
typedef unsigned long long u64;
typedef __attribute__((ext_vector_type(8)))  _Float16 f16x8;
typedef __attribute__((ext_vector_type(16))) float    f32x16;
typedef __attribute__((ext_vector_type(4)))  float    f32x4;
typedef __attribute__((ext_vector_type(4)))  uint     u32x4;
typedef __attribute__((ext_vector_type(2)))  int      i32x2;
typedef __attribute__((ext_vector_type(2)))  float    f32x2;

__device__ __forceinline__ int rfl_i(int x) {
    return __builtin_amdgcn_readfirstlane(x);
}

// rec = (w:f32 << 32) | (nloc:6b << 22) | (e:22b).
// PAD sentinel: e field = 0x3FFFFF (> any real e; host guards E < 2^22).
__device__ __forceinline__ u64 padrec(int) {
    return (u64)0x3FFFFFu;
}
__device__ __forceinline__ void store_line(u64* dst, const u64* l) {
    u32x4* d4 = (u32x4*)dst;
    #pragma unroll
    for (int i = 0; i < 4; ++i) {
        u32x4 v;
        v.x = (uint)l[2 * i];     v.y = (uint)(l[2 * i] >> 32);
        v.z = (uint)l[2 * i + 1]; v.w = (uint)(l[2 * i + 1] >> 32);
        d4[i] = v;
    }
}

// ---- pass 1: LDS-binned scatter; ALL stores are full 64B lines (8 recs) ----
// Flush-list: the thread whose insert fills a bin's 8th slot appends the bin
// id; the flush phase touches only listed bins (was: scan all 1563/round).
__global__ __launch_bounds__(256) void scatter_bin(
    const int* __restrict__ idx, const float* __restrict__ wts,
    int* __restrict__ gcur, u64* __restrict__ recs, int* __restrict__ flag, int E)
{
    __shared__ u64 slot[NBUCK][SLOTS];   // 125 KB
    __shared__ int cnt[NBUCK];           // 6.2 KB
    __shared__ u16 flist[FCAP];
    __shared__ int fln;

    const int tid = threadIdx.x;
    for (int b2 = tid; b2 < NBUCK; b2 += 256) cnt[b2] = 0;
    if (tid == 0) fln = 0;
    __syncthreads();

    const int chunk = (((E + SGRID - 1) / SGRID) + 511) & ~511;
    const int e0 = blockIdx.x * chunk;
    const int e1 = min(e0 + chunk, E);

#define INS(nn, ww, ee) do {                                                   \
    int bin_ = (nn) >> 6;                                                      \
    u64 rec_ = ((u64)__float_as_uint(ww) << 32)                                \
             | (uint)(ee) | ((uint)((nn) & 63) << 22);                         \
    int pos_ = atomicAdd(&cnt[bin_], 1);                                       \
    if (pos_ < SLOTS) {                                                        \
        slot[bin_][pos_] = rec_;                                               \
        if (pos_ == 7) {                                                       \
            int fp_ = atomicAdd(&fln, 1);                                      \
            if (fp_ < FCAP) flist[fp_] = (u16)bin_;                            \
        }                                                                      \
    } else {                                                                   \
        int gp_ = atomicAdd(&gcur[(size_t)bin_ * 32], 8);                      \
        if (gp_ + 8 <= RCAP) {                                                 \
            u64 line_[8];                                                      \
            line_[0] = rec_;                                                   \
            _Pragma("unroll")                                                  \
            for (int i_ = 1; i_ < 8; ++i_) line_[i_] = padrec(gp_ + i_);       \
            store_line(recs + (size_t)bin_ * RCAP + gp_, line_);               \
        } else *flag = 1;                                                      \
    }                                                                          \
} while (0)

    for (int base = e0; base < e1; base += 512) {
        int e = base + tid * 2;
        if (e + 1 < e1) {
            i32x2 n2 = __builtin_nontemporal_load((const i32x2*)(idx + e));
            f32x2 w2 = __builtin_nontemporal_load((const f32x2*)(wts + e));
            INS(n2.x, w2.x, e);
            INS(n2.y, w2.y, e + 1);
        } else if (e < e1) {
            int   n1 = idx[e];
            float w1 = wts[e];
            INS(n1, w1, e);
        }
        __syncthreads();
        int nf = fln; if (nf > FCAP) nf = FCAP;
        for (int i2 = tid; i2 < nf; i2 += 256) {
            int b2 = flist[i2];
            int c = cnt[b2]; if (c > SLOTS) c = SLOTS;
            if (c >= 8) {
                int gp = atomicAdd(&gcur[(size_t)b2 * 32], 8);
                if (gp + 8 <= RCAP) {
                    u64 line[8];
                    #pragma unroll
                    for (int i = 0; i < 8; ++i) line[i] = slot[b2][i];
                    store_line(recs + (size_t)b2 * RCAP + gp, line);
                } else *flag = 1;
                int rem = c - 8;
                #pragma unroll
                for (int i = 0; i < 2; ++i) if (i < rem) slot[b2][i] = slot[b2][8 + i];
                cnt[b2] = rem;
            }
        }
        __syncthreads();
        if (tid == 0) fln = 0;
        __syncthreads();
    }
#undef INS

    // final flush: pad to full lines (sentinel recs, skipped by gather)
    for (int b2 = tid; b2 < NBUCK; b2 += 256) {
        int c = cnt[b2]; if (c > SLOTS) c = SLOTS;
        if (c > 0) {
            int res = (c > 8) ? 16 : 8;
            int gp = atomicAdd(&gcur[(size_t)b2 * 32], res);
            if (gp + res <= RCAP) {
                u64 line[8];
                #pragma unroll
                for (int i = 0; i < 8; ++i)
                    line[i] = (i < c) ? slot[b2][i] : padrec(gp + i);
                store_line(recs + (size_t)b2 * RCAP + gp, line);
                if (c > 8) {
                    u64 line2[8];
                    #pragma unroll
                    for (int i = 0; i < 8; ++i)
                        line2[i] = (8 + i < c) ? slot[b2][8 + i] : padrec(gp + 8 + i);
                    store_line(recs + (size_t)b2 * RCAP + gp + 8, line2);
                }
            } else *flag = 1;
        }
    }
}

// ---- pass 2 (sort+gather): one block per 32-node HALF-region; grid 3126 ----
// EXACT R20 structure (VGPR=60, no spill); ONLY GCAP changed 2048->1792
// (LDS 21.5->18 KB -> 8 blocks/CU, wave-capped).
// MFMA 32x32x16 f16 mappings (verified R5-R20):
//   A-frag: lane(ucol,h) supplies A[row=ucol][k=8h+j]
//   B-frag: lane supplies B[k=8h+j][n=ucol] (emb^T)
__global__ __launch_bounds__(256, 8) void sort_gather(
    const float* __restrict__ emb, const f32x4* __restrict__ cf4,
    const int* __restrict__ gcur, const u64* __restrict__ recs,
    float* __restrict__ out, int* __restrict__ flag)
{
    __shared__ u64 lraw[GCAP];            // 14 KB
    __shared__ u16 perm[GCAP];            // 3.5 KB
    __shared__ int hist[GNPB], lcur[GNPB], lstart[GNPB];
    __shared__ float lden[GNPB];
    __shared__ int nkeep;

    if (*flag) return;
    const int tid  = threadIdx.x;
    const int l    = tid & 63;
    const int wv   = tid >> 6;
    const int ucol = l & 31;
    const int h    = l >> 5;
    const int r    = blockIdx.x >> 1;
    const int half = blockIdx.x & 1;

    if (tid < GNPB) { hist[tid] = 0; lden[tid] = 0.f; }
    if (tid == 0) nkeep = 0;
    __syncthreads();

    int n = gcur[(size_t)r * 32]; if (n > RCAP) n = RCAP;
    const u64* rbase = recs + (size_t)r * RCAP;

    // A: filter (pads excluded in the same branch) + append + hist + den
    for (int i = tid; i < n; i += 256) {
        u64 rec = rbase[i];
        int nl = (int)((rec >> 22) & 63u);
        bool real = ((uint)rec & 0x3FFFFFu) != 0x3FFFFFu;
        if (real && (nl >> 5) == half) {
            int pos = atomicAdd(&nkeep, 1);
            if (pos < GCAP) lraw[pos] = rec;
            atomicAdd(&hist[nl & 31], 1);
            atomicAdd(&lden[nl & 31], __uint_as_float((uint)(rec >> 32)));
        }
    }
    __syncthreads();
    int nk = nkeep;
    if (nk > GCAP) { if (tid == 0) *flag = 1; return; }

    // B: 32-lane exclusive scan
    if (tid < GNPB) {
        int c = hist[tid];
        int x = c;
        #pragma unroll
        for (int d = 1; d < GNPB; d <<= 1) {
            int v = __shfl_up(x, d);
            if (tid >= d) x += v;
        }
        lstart[tid] = x - c;
        lcur[tid]   = x - c;
    }
    __syncthreads();

    // C: rank -> perm
    for (int i = tid; i < nk; i += 256) {
        u64 rec = lraw[i];
        int d = atomicAdd(&lcur[(int)((rec >> 22) & 31u)], 1);
        perm[d] = (u16)i;
    }
    __syncthreads();

    // D: node-pair loop (R18-proven; 4 loads in flight, MFMAs sequential)
    f16x8 bf0, bf1;
    #pragma unroll
    for (int j = 0; j < 8; ++j) {
        bf0[j] = (_Float16)emb[ucol * 16 + 8 * h + j];
        bf1[j] = (_Float16)emb[(ucol + 32) * 16 + 8 * h + j];
    }
    f32x16 zacc;
    #pragma unroll
    for (int i = 0; i < 16; ++i) zacc[i] = 0.f;

    for (int j = 0; j < GNPB; j += 8) {
        const int nlA = wv + j;
        const int nlB = wv + j + 4;
        const int sA = lstart[nlA], cA = hist[nlA];
        const int sB = lstart[nlB], cB = hist[nlB];
        const int cmax = (cA > cB) ? cA : cB;
        float r0A = 0.f, r1A = 0.f, r0B = 0.f, r1B = 0.f;
        for (int ch = 0; ch < cmax; ch += 32) {
            bool vA = (ch + ucol) < cA;
            bool vB = (ch + ucol) < cB;
            u64 recA = lraw[perm[vA ? (sA + ch + ucol) : 0]];
            u64 recB = lraw[perm[vB ? (sB + ch + ucol) : 0]];
            float wA = vA ? __uint_as_float((uint)(recA >> 32)) : 0.f;
            float wB = vB ? __uint_as_float((uint)(recB >> 32)) : 0.f;
            int eA = (int)((uint)recA & 0x3FFFFFu);
            int eB = (int)((uint)recB & 0x3FFFFFu);
            // all 4 random-line loads issued before any MFMA
            f32x4 a0 = cf4[(size_t)eA * 4 + 2 * h];
            f32x4 a1 = cf4[(size_t)eA * 4 + 2 * h + 1];
            f32x4 b0 = cf4[(size_t)eB * 4 + 2 * h];
            f32x4 b1 = cf4[(size_t)eB * 4 + 2 * h + 1];
            {   // node A: sequential MFMA+reduce, one f32x16 live
                f16x8 fa;
                fa[0] = (_Float16)(a0.x * wA); fa[1] = (_Float16)(a0.y * wA);
                fa[2] = (_Float16)(a0.z * wA); fa[3] = (_Float16)(a0.w * wA);
                fa[4] = (_Float16)(a1.x * wA); fa[5] = (_Float16)(a1.y * wA);
                fa[6] = (_Float16)(a1.z * wA); fa[7] = (_Float16)(a1.w * wA);
                {
                    f32x16 d0 = __builtin_amdgcn_mfma_f32_32x32x16_f16(fa, bf0, zacc, 0, 0, 0);
                    float t = 0.f;
                    #pragma unroll
                    for (int r2 = 0; r2 < 16; ++r2) t += fmaxf(d0[r2], 0.f);
                    r0A += t;
                }
                {
                    f32x16 d1 = __builtin_amdgcn_mfma_f32_32x32x16_f16(fa, bf1, zacc, 0, 0, 0);
                    float t = 0.f;
                    #pragma unroll
                    for (int r2 = 0; r2 < 16; ++r2) t += fmaxf(d1[r2], 0.f);
                    r1A += t;
                }
            }
            {   // node B
                f16x8 fb;
                fb[0] = (_Float16)(b0.x * wB); fb[1] = (_Float16)(b0.y * wB);
                fb[2] = (_Float16)(b0.z * wB); fb[3] = (_Float16)(b0.w * wB);
                fb[4] = (_Float16)(b1.x * wB); fb[5] = (_Float16)(b1.y * wB);
                fb[6] = (_Float16)(b1.z * wB); fb[7] = (_Float16)(b1.w * wB);
                {
                    f32x16 d0 = __builtin_amdgcn_mfma_f32_32x32x16_f16(fb, bf0, zacc, 0, 0, 0);
                    float t = 0.f;
                    #pragma unroll
                    for (int r2 = 0; r2 < 16; ++r2) t += fmaxf(d0[r2], 0.f);
                    r0B += t;
                }
                {
                    f32x16 d1 = __builtin_amdgcn_mfma_f32_32x32x16_f16(fb, bf1, zacc, 0, 0, 0);
                    float t = 0.f;
                    #pragma unroll
                    for (int r2 = 0; r2 < 16; ++r2) t += fmaxf(d1[r2], 0.f);
                    r1B += t;
                }
            }
        }
        r0A += __shfl_xor(r0A, 32); r1A += __shfl_xor(r1A, 32);
        r0B += __shfl_xor(r0B, 32); r1B += __shfl_xor(r1B, 32);
        int nodeA = r * NPB + half * 32 + nlA;
        int nodeB = r * NPB + half * 32 + nlB;
        if (nodeA < NODES)
            out[(size_t)nodeA * 64 + l] = (h ? r1A : r0A) / lden[nlA];
        if (nodeB < NODES)
            out[(size_t)nodeB * 64 + l] = (h ? r1B : r0B) / lden[nlB];
    }
}

// ================= guarded fallbacks (no-op when flag==0 / null) =================

__global__ __launch_bounds__(256) void zero_fb(
    float* __restrict__ out, float* __restrict__ den, int nout,
    const int* __restrict__ flag)
{
    if (flag && !*flag) return;
    int i = blockIdx.x * blockDim.x + threadIdx.x;
    int stride = gridDim.x * blockDim.x;
    for (int j = i; j < nout; j += stride) out[j] = 0.f;
    for (int j = i; j < NODES; j += stride) den[j] = 0.f;
}

__global__ __launch_bounds__(256) void edge_scatter_fb(
    const float* __restrict__ emb, const float* __restrict__ cf,
    const float* __restrict__ wts, const int* __restrict__ idx,
    float* __restrict__ num, float* __restrict__ den, int E,
    const int* __restrict__ flag)
{
    if (flag && !*flag) return;
    const int lane = threadIdx.x & 63;
    float er[16];
    #pragma unroll
    for (int f = 0; f < 16; ++f) er[f] = emb[lane * 16 + f];
    int wid = rfl_i((int)((blockIdx.x * blockDim.x + threadIdx.x) >> 6));
    int nw = (gridDim.x * blockDim.x) >> 6;
    for (int e = wid; e < E; e += nw) {
        const float* c = cf + (size_t)e * 16;
        float a = 0.f;
        #pragma unroll
        for (int f = 0; f < 16; ++f) a = fmaf(c[f], er[f], a);
        float wv = wts[e];
        int n = idx[e];
        unsafeAtomicAdd(num + (size_t)n * 64 + lane, fmaxf(a, 0.f) * wv);
        if (lane == 0) unsafeAtomicAdd(den + n, wv);
    }
}

__global__ __launch_bounds__(256) void divide_fb(
    float* __restrict__ out, const float* __restrict__ den, int nvec,
    const int* __restrict__ flag)
{
    if (flag && !*flag) return;
    int i = blockIdx.x * blockDim.x + threadIdx.x;
    int stride = gridDim.x * blockDim.x;
    float4* o4 = reinterpret_cast<float4*>(out);
    for (; i < nvec; i += stride) {
        float4 v = o4[i];
        float d = den[i >> 4];
        v.x /= d; v.y /= d; v.z /= d; v.w /= d;
        o4[i] = v;
    }
}

extern "C" void kernel_launch(void* const* d_in, const int* in_sizes, int n_in,
                              void* d_out, int out_size, void* d_ws, size_t ws_size,
                              hipStream_t stream)
{
    const float* emb = (const float*)d_in[0];   // (64,16)
    const float* cf  = (const float*)d_in[1];   // (E,16)
    const float* wts = (const float*)d_in[2];   // (E,)
    const int*   idx = (const int*)d_in[3];     // (E,)
    int E = in_sizes[2];
    float* out = (float*)d_out;

    // ws layout (~52 MB)
    char* p = (char*)d_ws;
    auto take = [&](size_t bytes) { char* r = p; p += (bytes + 255) & ~(size_t)255; return r; };
    int*  gcur = (int*)take((size_t)NBUCK * 32 * sizeof(int));    // 200 KB padded
    float* den = (float*)take((size_t)NODES * sizeof(float));     // fallback only
    int*  flag = (int*)take(256);
    u64*  recs = (u64*)take((size_t)NBUCK * RCAP * sizeof(u64));  // 51 MB fixed regions
    size_t need = (size_t)(p - (char*)d_ws);

    if (E < (1 << 22) && ws_size >= need) {
        (void)hipMemsetAsync(gcur, 0, (size_t)NBUCK * 32 * sizeof(int), stream);
        (void)hipMemsetAsync(flag, 0, sizeof(int), stream);
        scatter_bin<<<SGRID, 256, 0, stream>>>(idx, wts, gcur, recs, flag, E);
        sort_gather<<<NBUCK * 2, 256, 0, stream>>>(
            emb, (const f32x4*)cf, gcur, recs, out, flag);
        // guarded fallback chain (no-ops when flag==0)
        zero_fb<<<2048, 256, 0, stream>>>(out, den, out_size, flag);
        edge_scatter_fb<<<4096, 256, 0, stream>>>(emb, cf, wts, idx, out, den, E, flag);
        divide_fb<<<2048, 256, 0, stream>>>(out, den, out_size / 4, flag);
    } else {
        // host fallback: plain atomic scatter (needs only NODES floats of ws)
        float* den2 = (float*)d_ws;
        (void)hipMemsetAsync(d_out, 0, (size_t)out_size * sizeof(float), stream);
        (void)hipMemsetAsync(d_ws, 0, (size_t)NODES * sizeof(float), stream);
        edge_scatter_fb<<<4096, 256, 0, stream>>>(emb, cf, wts, idx, out, den2, E, nullptr);
        divide_fb<<<2048, 256, 0, stream>>>(out, den2, out_size / 4, nullptr);
    }
}

// Round 22
// 162.574 us; speedup vs baseline: 2.7639x; 2.7639x over previous
//
#include <hip/hip_runtime.h>
#include <cstddef>

constexpr int NODES = 100000;
constexpr int NPB   = 64;                      // nodes per scatter bin / region
constexpr int NBUCK = (NODES + NPB - 1) / NPB; // 1563
constexpr int RCAP  = 4096;                    // recs per region (mean ~3200 incl pads)
constexpr int SLOTS = 10;                      // LDS slots per bin (flush at 8)
constexpr int SGRID = 256;                     // scatter blocks (1/CU)
constexpr int GNPB  = 32;                      // nodes per gather block (half region)
constexpr int GCAP  = 2048;                    // FROZEN: any other value triggers spill (R19/R21)
constexpr int FCAP  = 128;                     // flush-list capacity

typedef unsigned int uint;
typedef unsigned short u16;
typedef unsigned long long u64;
typedef __attribute__((ext_vector_type(8)))  _Float16 f16x8;
typedef __attribute__((ext_vector_type(16))) float    f32x16;
typedef __attribute__((ext_vector_type(4)))  float    f32x4;
typedef __attribute__((ext_vector_type(4)))  uint     u32x4;
typedef __attribute__((ext_vector_type(2)))  int      i32x2;
typedef __attribute__((ext_vector_type(2)))  float    f32x2;

__device__ __forceinline__ int rfl_i(int x) {
    return __builtin_amdgcn_readfirstlane(x);
}

// rec = (w:f32 << 32) | (nloc:6b << 22) | (e:22b).
// PAD sentinel: e field = 0x3FFFFF (> any real e; host guards E < 2^22).
__device__ __forceinline__ u64 padrec(int) {
    return (u64)0x3FFFFFu;
}
__device__ __forceinline__ void store_line(u64* dst, const u64* l) {
    u32x4* d4 = (u32x4*)dst;
    #pragma unroll
    for (int i = 0; i < 4; ++i) {
        u32x4 v;
        v.x = (uint)l[2 * i];     v.y = (uint)(l[2 * i] >> 32);
        v.z = (uint)l[2 * i + 1]; v.w = (uint)(l[2 * i + 1] >> 32);
        d4[i] = v;
    }
}

// ---- pass 1: LDS-binned scatter; ALL stores are full 64B lines (8 recs) ----
// Flush-list (R21): the thread whose insert fills a bin's 8th slot appends the
// bin id; the flush phase touches only listed bins (was: scan all 1563/round).
__global__ __launch_bounds__(256) void scatter_bin(
    const int* __restrict__ idx, const float* __restrict__ wts,
    int* __restrict__ gcur, u64* __restrict__ recs, int* __restrict__ flag, int E)
{
    __shared__ u64 slot[NBUCK][SLOTS];   // 125 KB
    __shared__ int cnt[NBUCK];           // 6.2 KB
    __shared__ u16 flist[FCAP];
    __shared__ int fln;

    const int tid = threadIdx.x;
    for (int b2 = tid; b2 < NBUCK; b2 += 256) cnt[b2] = 0;
    if (tid == 0) fln = 0;
    __syncthreads();

    const int chunk = (((E + SGRID - 1) / SGRID) + 511) & ~511;
    const int e0 = blockIdx.x * chunk;
    const int e1 = min(e0 + chunk, E);

#define INS(nn, ww, ee) do {                                                   \
    int bin_ = (nn) >> 6;                                                      \
    u64 rec_ = ((u64)__float_as_uint(ww) << 32)                                \
             | (uint)(ee) | ((uint)((nn) & 63) << 22);                         \
    int pos_ = atomicAdd(&cnt[bin_], 1);                                       \
    if (pos_ < SLOTS) {                                                        \
        slot[bin_][pos_] = rec_;                                               \
        if (pos_ == 7) {                                                       \
            int fp_ = atomicAdd(&fln, 1);                                      \
            if (fp_ < FCAP) flist[fp_] = (u16)bin_;                            \
        }                                                                      \
    } else {                                                                   \
        int gp_ = atomicAdd(&gcur[(size_t)bin_ * 32], 8);                      \
        if (gp_ + 8 <= RCAP) {                                                 \
            u64 line_[8];                                                      \
            line_[0] = rec_;                                                   \
            _Pragma("unroll")                                                  \
            for (int i_ = 1; i_ < 8; ++i_) line_[i_] = padrec(gp_ + i_);       \
            store_line(recs + (size_t)bin_ * RCAP + gp_, line_);               \
        } else *flag = 1;                                                      \
    }                                                                          \
} while (0)

    for (int base = e0; base < e1; base += 512) {
        int e = base + tid * 2;
        if (e + 1 < e1) {
            i32x2 n2 = __builtin_nontemporal_load((const i32x2*)(idx + e));
            f32x2 w2 = __builtin_nontemporal_load((const f32x2*)(wts + e));
            INS(n2.x, w2.x, e);
            INS(n2.y, w2.y, e + 1);
        } else if (e < e1) {
            int   n1 = idx[e];
            float w1 = wts[e];
            INS(n1, w1, e);
        }
        __syncthreads();
        int nf = fln; if (nf > FCAP) nf = FCAP;
        for (int i2 = tid; i2 < nf; i2 += 256) {
            int b2 = flist[i2];
            int c = cnt[b2]; if (c > SLOTS) c = SLOTS;
            if (c >= 8) {
                int gp = atomicAdd(&gcur[(size_t)b2 * 32], 8);
                if (gp + 8 <= RCAP) {
                    u64 line[8];
                    #pragma unroll
                    for (int i = 0; i < 8; ++i) line[i] = slot[b2][i];
                    store_line(recs + (size_t)b2 * RCAP + gp, line);
                } else *flag = 1;
                int rem = c - 8;
                #pragma unroll
                for (int i = 0; i < 2; ++i) if (i < rem) slot[b2][i] = slot[b2][8 + i];
                cnt[b2] = rem;
            }
        }
        __syncthreads();
        if (tid == 0) fln = 0;
        __syncthreads();
    }
#undef INS

    // final flush: pad to full lines (sentinel recs, skipped by gather)
    for (int b2 = tid; b2 < NBUCK; b2 += 256) {
        int c = cnt[b2]; if (c > SLOTS) c = SLOTS;
        if (c > 0) {
            int res = (c > 8) ? 16 : 8;
            int gp = atomicAdd(&gcur[(size_t)b2 * 32], res);
            if (gp + res <= RCAP) {
                u64 line[8];
                #pragma unroll
                for (int i = 0; i < 8; ++i)
                    line[i] = (i < c) ? slot[b2][i] : padrec(gp + i);
                store_line(recs + (size_t)b2 * RCAP + gp, line);
                if (c > 8) {
                    u64 line2[8];
                    #pragma unroll
                    for (int i = 0; i < 8; ++i)
                        line2[i] = (8 + i < c) ? slot[b2][8 + i] : padrec(gp + 8 + i);
                    store_line(recs + (size_t)b2 * RCAP + gp + 8, line2);
                }
            } else *flag = 1;
        }
    }
}

// ---- pass 2 (sort+gather): BYTE-EXACT R20 kernel (205us proven, VGPR=60) ----
// GCAP=2048 FROZEN. MFMA 32x32x16 f16 mappings (verified R5-R20):
//   A-frag: lane(ucol,h) supplies A[row=ucol][k=8h+j]
//   B-frag: lane supplies B[k=8h+j][n=ucol] (emb^T)
__global__ __launch_bounds__(256, 8) void sort_gather(
    const float* __restrict__ emb, const f32x4* __restrict__ cf4,
    const int* __restrict__ gcur, const u64* __restrict__ recs,
    float* __restrict__ out, int* __restrict__ flag)
{
    __shared__ u64 lraw[GCAP];            // 16 KB
    __shared__ u16 perm[GCAP];            // 4 KB
    __shared__ int hist[GNPB], lcur[GNPB], lstart[GNPB];
    __shared__ float lden[GNPB];
    __shared__ int nkeep;

    if (*flag) return;
    const int tid  = threadIdx.x;
    const int l    = tid & 63;
    const int wv   = tid >> 6;
    const int ucol = l & 31;
    const int h    = l >> 5;
    const int r    = blockIdx.x >> 1;
    const int half = blockIdx.x & 1;

    if (tid < GNPB) { hist[tid] = 0; lden[tid] = 0.f; }
    if (tid == 0) nkeep = 0;
    __syncthreads();

    int n = gcur[(size_t)r * 32]; if (n > RCAP) n = RCAP;
    const u64* rbase = recs + (size_t)r * RCAP;

    // A: filter (pads excluded in the same branch) + append + hist + den
    for (int i = tid; i < n; i += 256) {
        u64 rec = rbase[i];
        int nl = (int)((rec >> 22) & 63u);
        bool real = ((uint)rec & 0x3FFFFFu) != 0x3FFFFFu;
        if (real && (nl >> 5) == half) {
            int pos = atomicAdd(&nkeep, 1);
            if (pos < GCAP) lraw[pos] = rec;
            atomicAdd(&hist[nl & 31], 1);
            atomicAdd(&lden[nl & 31], __uint_as_float((uint)(rec >> 32)));
        }
    }
    __syncthreads();
    int nk = nkeep;
    if (nk > GCAP) { if (tid == 0) *flag = 1; return; }

    // B: 32-lane exclusive scan
    if (tid < GNPB) {
        int c = hist[tid];
        int x = c;
        #pragma unroll
        for (int d = 1; d < GNPB; d <<= 1) {
            int v = __shfl_up(x, d);
            if (tid >= d) x += v;
        }
        lstart[tid] = x - c;
        lcur[tid]   = x - c;
    }
    __syncthreads();

    // C: rank -> perm
    for (int i = tid; i < nk; i += 256) {
        u64 rec = lraw[i];
        int d = atomicAdd(&lcur[(int)((rec >> 22) & 31u)], 1);
        perm[d] = (u16)i;
    }
    __syncthreads();

    // D: node-pair loop (R18-proven; 4 loads in flight, MFMAs sequential)
    f16x8 bf0, bf1;
    #pragma unroll
    for (int j = 0; j < 8; ++j) {
        bf0[j] = (_Float16)emb[ucol * 16 + 8 * h + j];
        bf1[j] = (_Float16)emb[(ucol + 32) * 16 + 8 * h + j];
    }
    f32x16 zacc;
    #pragma unroll
    for (int i = 0; i < 16; ++i) zacc[i] = 0.f;

    for (int j = 0; j < GNPB; j += 8) {
        const int nlA = wv + j;
        const int nlB = wv + j + 4;
        const int sA = lstart[nlA], cA = hist[nlA];
        const int sB = lstart[nlB], cB = hist[nlB];
        const int cmax = (cA > cB) ? cA : cB;
        float r0A = 0.f, r1A = 0.f, r0B = 0.f, r1B = 0.f;
        for (int ch = 0; ch < cmax; ch += 32) {
            bool vA = (ch + ucol) < cA;
            bool vB = (ch + ucol) < cB;
            u64 recA = lraw[perm[vA ? (sA + ch + ucol) : 0]];
            u64 recB = lraw[perm[vB ? (sB + ch + ucol) : 0]];
            float wA = vA ? __uint_as_float((uint)(recA >> 32)) : 0.f;
            float wB = vB ? __uint_as_float((uint)(recB >> 32)) : 0.f;
            int eA = (int)((uint)recA & 0x3FFFFFu);
            int eB = (int)((uint)recB & 0x3FFFFFu);
            // all 4 random-line loads issued before any MFMA
            f32x4 a0 = cf4[(size_t)eA * 4 + 2 * h];
            f32x4 a1 = cf4[(size_t)eA * 4 + 2 * h + 1];
            f32x4 b0 = cf4[(size_t)eB * 4 + 2 * h];
            f32x4 b1 = cf4[(size_t)eB * 4 + 2 * h + 1];
            {   // node A: sequential MFMA+reduce, one f32x16 live
                f16x8 fa;
                fa[0] = (_Float16)(a0.x * wA); fa[1] = (_Float16)(a0.y * wA);
                fa[2] = (_Float16)(a0.z * wA); fa[3] = (_Float16)(a0.w * wA);
                fa[4] = (_Float16)(a1.x * wA); fa[5] = (_Float16)(a1.y * wA);
                fa[6] = (_Float16)(a1.z * wA); fa[7] = (_Float16)(a1.w * wA);
                {
                    f32x16 d0 = __builtin_amdgcn_mfma_f32_32x32x16_f16(fa, bf0, zacc, 0, 0, 0);
                    float t = 0.f;
                    #pragma unroll
                    for (int r2 = 0; r2 < 16; ++r2) t += fmaxf(d0[r2], 0.f);
                    r0A += t;
                }
                {
                    f32x16 d1 = __builtin_amdgcn_mfma_f32_32x32x16_f16(fa, bf1, zacc, 0, 0, 0);
                    float t = 0.f;
                    #pragma unroll
                    for (int r2 = 0; r2 < 16; ++r2) t += fmaxf(d1[r2], 0.f);
                    r1A += t;
                }
            }
            {   // node B
                f16x8 fb;
                fb[0] = (_Float16)(b0.x * wB); fb[1] = (_Float16)(b0.y * wB);
                fb[2] = (_Float16)(b0.z * wB); fb[3] = (_Float16)(b0.w * wB);
                fb[4] = (_Float16)(b1.x * wB); fb[5] = (_Float16)(b1.y * wB);
                fb[6] = (_Float16)(b1.z * wB); fb[7] = (_Float16)(b1.w * wB);
                {
                    f32x16 d0 = __builtin_amdgcn_mfma_f32_32x32x16_f16(fb, bf0, zacc, 0, 0, 0);
                    float t = 0.f;
                    #pragma unroll
                    for (int r2 = 0; r2 < 16; ++r2) t += fmaxf(d0[r2], 0.f);
                    r0B += t;
                }
                {
                    f32x16 d1 = __builtin_amdgcn_mfma_f32_32x32x16_f16(fb, bf1, zacc, 0, 0, 0);
                    float t = 0.f;
                    #pragma unroll
                    for (int r2 = 0; r2 < 16; ++r2) t += fmaxf(d1[r2], 0.f);
                    r1B += t;
                }
            }
        }
        r0A += __shfl_xor(r0A, 32); r1A += __shfl_xor(r1A, 32);
        r0B += __shfl_xor(r0B, 32); r1B += __shfl_xor(r1B, 32);
        int nodeA = r * NPB + half * 32 + nlA;
        int nodeB = r * NPB + half * 32 + nlB;
        if (nodeA < NODES)
            out[(size_t)nodeA * 64 + l] = (h ? r1A : r0A) / lden[nlA];
        if (nodeB < NODES)
            out[(size_t)nodeB * 64 + l] = (h ? r1B : r0B) / lden[nlB];
    }
}

// ================= guarded fallbacks (no-op when flag==0 / null) =================

__global__ __launch_bounds__(256) void zero_fb(
    float* __restrict__ out, float* __restrict__ den, int nout,
    const int* __restrict__ flag)
{
    if (flag && !*flag) return;
    int i = blockIdx.x * blockDim.x + threadIdx.x;
    int stride = gridDim.x * blockDim.x;
    for (int j = i; j < nout; j += stride) out[j] = 0.f;
    for (int j = i; j < NODES; j += stride) den[j] = 0.f;
}

__global__ __launch_bounds__(256) void edge_scatter_fb(
    const float* __restrict__ emb, const float* __restrict__ cf,
    const float* __restrict__ wts, const int* __restrict__ idx,
    float* __restrict__ num, float* __restrict__ den, int E,
    const int* __restrict__ flag)
{
    if (flag && !*flag) return;
    const int lane = threadIdx.x & 63;
    float er[16];
    #pragma unroll
    for (int f = 0; f < 16; ++f) er[f] = emb[lane * 16 + f];
    int wid = rfl_i((int)((blockIdx.x * blockDim.x + threadIdx.x) >> 6));
    int nw = (gridDim.x * blockDim.x) >> 6;
    for (int e = wid; e < E; e += nw) {
        const float* c = cf + (size_t)e * 16;
        float a = 0.f;
        #pragma unroll
        for (int f = 0; f < 16; ++f) a = fmaf(c[f], er[f], a);
        float wv = wts[e];
        int n = idx[e];
        unsafeAtomicAdd(num + (size_t)n * 64 + lane, fmaxf(a, 0.f) * wv);
        if (lane == 0) unsafeAtomicAdd(den + n, wv);
    }
}

__global__ __launch_bounds__(256) void divide_fb(
    float* __restrict__ out, const float* __restrict__ den, int nvec,
    const int* __restrict__ flag)
{
    if (flag && !*flag) return;
    int i = blockIdx.x * blockDim.x + threadIdx.x;
    int stride = gridDim.x * blockDim.x;
    float4* o4 = reinterpret_cast<float4*>(out);
    for (; i < nvec; i += stride) {
        float4 v = o4[i];
        float d = den[i >> 4];
        v.x /= d; v.y /= d; v.z /= d; v.w /= d;
        o4[i] = v;
    }
}

extern "C" void kernel_launch(void* const* d_in, const int* in_sizes, int n_in,
                              void* d_out, int out_size, void* d_ws, size_t ws_size,
                              hipStream_t stream)
{
    const float* emb = (const float*)d_in[0];   // (64,16)
    const float* cf  = (const float*)d_in[1];   // (E,16)
    const float* wts = (const float*)d_in[2];   // (E,)
    const int*   idx = (const int*)d_in[3];     // (E,)
    int E = in_sizes[2];
    float* out = (float*)d_out;

    // ws layout (~52 MB)
    char* p = (char*)d_ws;
    auto take = [&](size_t bytes) { char* r = p; p += (bytes + 255) & ~(size_t)255; return r; };
    int*  gcur = (int*)take((size_t)NBUCK * 32 * sizeof(int));    // 200 KB padded
    float* den = (float*)take((size_t)NODES * sizeof(float));     // fallback only
    int*  flag = (int*)take(256);
    u64*  recs = (u64*)take((size_t)NBUCK * RCAP * sizeof(u64));  // 51 MB fixed regions
    size_t need = (size_t)(p - (char*)d_ws);

    if (E < (1 << 22) && ws_size >= need) {
        (void)hipMemsetAsync(gcur, 0, (size_t)NBUCK * 32 * sizeof(int), stream);
        (void)hipMemsetAsync(flag, 0, sizeof(int), stream);
        scatter_bin<<<SGRID, 256, 0, stream>>>(idx, wts, gcur, recs, flag, E);
        sort_gather<<<NBUCK * 2, 256, 0, stream>>>(
            emb, (const f32x4*)cf, gcur, recs, out, flag);
        // guarded fallback chain (no-ops when flag==0)
        zero_fb<<<2048, 256, 0, stream>>>(out, den, out_size, flag);
        edge_scatter_fb<<<4096, 256, 0, stream>>>(emb, cf, wts, idx, out, den, E, flag);
        divide_fb<<<2048, 256, 0, stream>>>(out, den, out_size / 4, flag);
    } else {
        // host fallback: plain atomic scatter (needs only NODES floats of ws)
        float* den2 = (float*)d_ws;
        (void)hipMemsetAsync(d_out, 0, (size_t)out_size * sizeof(float), stream);
        (void)hipMemsetAsync(d_ws, 0, (size_t)NODES * sizeof(float), stream);
        edge_scatter_fb<<<4096, 256, 0, stream>>>(emb, cf, wts, idx, out, den2, E, nullptr);
        divide_fb<<<2048, 256, 0, stream>>>(out, den2, out_size / 4, nullptr);
    }
}

// Round 23
// 160.958 us; speedup vs baseline: 2.7917x; 1.0100x over previous
//
#include <hip/hip_runtime.h>
#include <cstddef>

constexpr int NODES = 100000;
constexpr int NPB   = 64;                      // nodes per scatter bin / region
constexpr int NBUCK = (NODES + NPB - 1) / NPB; // 1563
constexpr int RCAP  = 4096;                    // recs per region (mean ~3200 incl pads)
constexpr int SLOTS = 10;                      // LDS slots per bin (flush at 8)
constexpr int SGRID = 256;                     // scatter blocks (1/CU)
constexpr int GNPB  = 64;                      // nodes per gather block (FULL region)
constexpr int GCAP  = 4096;                    // gather lraw capacity (full region)
constexpr int FCAP  = 128;                     // flush-list capacity

typedef unsigned int uint;
typedef unsigned short u16;
typedef unsigned long long u64;
typedef __attribute__((ext_vector_type(8)))  _Float16 f16x8;
typedef __attribute__((ext_vector_type(16))) float    f32x16;
typedef __attribute__((ext_vector_type(4)))  float    f32x4;
typedef __attribute__((ext_vector_type(4)))  uint     u32x4;
typedef __attribute__((ext_vector_type(2)))  int      i32x2;
typedef __attribute__((ext_vector_type(2)))  float    f32x2;

__device__ __forceinline__ int rfl_i(int x) {
    return __builtin_amdgcn_readfirstlane(x);
}

// rec = (w:f32 << 32) | (nloc:6b << 22) | (e:22b).
// PAD sentinel: e field = 0x3FFFFF (> any real e; host guards E < 2^22).
__device__ __forceinline__ u64 padrec(int) {
    return (u64)0x3FFFFFu;
}
__device__ __forceinline__ void store_line(u64* dst, const u64* l) {
    u32x4* d4 = (u32x4*)dst;
    #pragma unroll
    for (int i = 0; i < 4; ++i) {
        u32x4 v;
        v.x = (uint)l[2 * i];     v.y = (uint)(l[2 * i] >> 32);
        v.z = (uint)l[2 * i + 1]; v.w = (uint)(l[2 * i + 1] >> 32);
        d4[i] = v;
    }
}

// ---- pass 1: LDS-binned scatter (R22-proven); full 64B-line stores only ----
__global__ __launch_bounds__(256) void scatter_bin(
    const int* __restrict__ idx, const float* __restrict__ wts,
    int* __restrict__ gcur, u64* __restrict__ recs, int* __restrict__ flag, int E)
{
    __shared__ u64 slot[NBUCK][SLOTS];   // 125 KB
    __shared__ int cnt[NBUCK];           // 6.2 KB
    __shared__ u16 flist[FCAP];
    __shared__ int fln;

    const int tid = threadIdx.x;
    for (int b2 = tid; b2 < NBUCK; b2 += 256) cnt[b2] = 0;
    if (tid == 0) fln = 0;
    __syncthreads();

    const int chunk = (((E + SGRID - 1) / SGRID) + 511) & ~511;
    const int e0 = blockIdx.x * chunk;
    const int e1 = min(e0 + chunk, E);

#define INS(nn, ww, ee) do {                                                   \
    int bin_ = (nn) >> 6;                                                      \
    u64 rec_ = ((u64)__float_as_uint(ww) << 32)                                \
             | (uint)(ee) | ((uint)((nn) & 63) << 22);                         \
    int pos_ = atomicAdd(&cnt[bin_], 1);                                       \
    if (pos_ < SLOTS) {                                                        \
        slot[bin_][pos_] = rec_;                                               \
        if (pos_ == 7) {                                                       \
            int fp_ = atomicAdd(&fln, 1);                                      \
            if (fp_ < FCAP) flist[fp_] = (u16)bin_;                            \
        }                                                                      \
    } else {                                                                   \
        int gp_ = atomicAdd(&gcur[(size_t)bin_ * 32], 8);                      \
        if (gp_ + 8 <= RCAP) {                                                 \
            u64 line_[8];                                                      \
            line_[0] = rec_;                                                   \
            _Pragma("unroll")                                                  \
            for (int i_ = 1; i_ < 8; ++i_) line_[i_] = padrec(gp_ + i_);       \
            store_line(recs + (size_t)bin_ * RCAP + gp_, line_);               \
        } else *flag = 1;                                                      \
    }                                                                          \
} while (0)

    for (int base = e0; base < e1; base += 512) {
        int e = base + tid * 2;
        if (e + 1 < e1) {
            i32x2 n2 = __builtin_nontemporal_load((const i32x2*)(idx + e));
            f32x2 w2 = __builtin_nontemporal_load((const f32x2*)(wts + e));
            INS(n2.x, w2.x, e);
            INS(n2.y, w2.y, e + 1);
        } else if (e < e1) {
            int   n1 = idx[e];
            float w1 = wts[e];
            INS(n1, w1, e);
        }
        __syncthreads();
        int nf = fln; if (nf > FCAP) nf = FCAP;
        for (int i2 = tid; i2 < nf; i2 += 256) {
            int b2 = flist[i2];
            int c = cnt[b2]; if (c > SLOTS) c = SLOTS;
            if (c >= 8) {
                int gp = atomicAdd(&gcur[(size_t)b2 * 32], 8);
                if (gp + 8 <= RCAP) {
                    u64 line[8];
                    #pragma unroll
                    for (int i = 0; i < 8; ++i) line[i] = slot[b2][i];
                    store_line(recs + (size_t)b2 * RCAP + gp, line);
                } else *flag = 1;
                int rem = c - 8;
                #pragma unroll
                for (int i = 0; i < 2; ++i) if (i < rem) slot[b2][i] = slot[b2][8 + i];
                cnt[b2] = rem;
            }
        }
        __syncthreads();
        if (tid == 0) fln = 0;
        __syncthreads();
    }
#undef INS

    // final flush: pad to full lines (sentinel recs, skipped by gather)
    for (int b2 = tid; b2 < NBUCK; b2 += 256) {
        int c = cnt[b2]; if (c > SLOTS) c = SLOTS;
        if (c > 0) {
            int res = (c > 8) ? 16 : 8;
            int gp = atomicAdd(&gcur[(size_t)b2 * 32], res);
            if (gp + res <= RCAP) {
                u64 line[8];
                #pragma unroll
                for (int i = 0; i < 8; ++i)
                    line[i] = (i < c) ? slot[b2][i] : padrec(gp + i);
                store_line(recs + (size_t)b2 * RCAP + gp, line);
                if (c > 8) {
                    u64 line2[8];
                    #pragma unroll
                    for (int i = 0; i < 8; ++i)
                        line2[i] = (8 + i < c) ? slot[b2][8 + i] : padrec(gp + 8 + i);
                    store_line(recs + (size_t)b2 * RCAP + gp + 8, line2);
                }
            } else *flag = 1;
        }
    }
}

// ---- pass 2 (sort+gather): 512-thread block per FULL 64-node region ----
// 8 waves/block x 3 blocks/CU (42KB LDS) = 24 waves/CU (2x R22 residency).
// D-loop body identical to R22's proven shape (node-pair, 4 loads in flight,
// sequential MFMA+reduce, one f32x16 live).
// MFMA 32x32x16 f16 mappings (verified R5-R22):
//   A-frag: lane(ucol,h) supplies A[row=ucol][k=8h+j]
//   B-frag: lane supplies B[k=8h+j][n=ucol] (emb^T)
__global__ __launch_bounds__(512) void sort_gather(
    const float* __restrict__ emb, const f32x4* __restrict__ cf4,
    const int* __restrict__ gcur, const u64* __restrict__ recs,
    float* __restrict__ out, int* __restrict__ flag)
{
    __shared__ u64 lraw[GCAP];            // 32 KB
    __shared__ u16 perm[GCAP];            // 8 KB
    __shared__ int hist[GNPB], lcur[GNPB], lstart[GNPB];
    __shared__ float lden[GNPB];
    __shared__ int nkeep;

    if (*flag) return;
    const int tid  = threadIdx.x;
    const int l    = tid & 63;
    const int wv   = tid >> 6;            // 0..7
    const int ucol = l & 31;
    const int h    = l >> 5;
    const int r    = blockIdx.x;

    if (tid < GNPB) { hist[tid] = 0; lden[tid] = 0.f; }
    if (tid == 0) nkeep = 0;
    __syncthreads();

    int n = gcur[(size_t)r * 32]; if (n > RCAP) n = RCAP;
    const u64* rbase = recs + (size_t)r * RCAP;

    // A: append real recs (pads excluded) + hist + den
    for (int i = tid; i < n; i += 512) {
        u64 rec = rbase[i];
        int nl = (int)((rec >> 22) & 63u);
        bool real = ((uint)rec & 0x3FFFFFu) != 0x3FFFFFu;
        if (real) {
            int pos = atomicAdd(&nkeep, 1);
            if (pos < GCAP) lraw[pos] = rec;
            atomicAdd(&hist[nl], 1);
            atomicAdd(&lden[nl], __uint_as_float((uint)(rec >> 32)));
        }
    }
    __syncthreads();
    int nk = nkeep;
    if (nk > GCAP) { if (tid == 0) *flag = 1; return; }

    // B: 64-lane exclusive scan (wave 0)
    if (tid < GNPB) {
        int c = hist[tid];
        int x = c;
        #pragma unroll
        for (int d = 1; d < GNPB; d <<= 1) {
            int v = __shfl_up(x, d);
            if (tid >= d) x += v;
        }
        lstart[tid] = x - c;
        lcur[tid]   = x - c;
    }
    __syncthreads();

    // C: rank -> perm
    for (int i = tid; i < nk; i += 512) {
        u64 rec = lraw[i];
        int d = atomicAdd(&lcur[(int)((rec >> 22) & 63u)], 1);
        perm[d] = (u16)i;
    }
    __syncthreads();

    // D: node-pair loop (R18/R22-proven body)
    f16x8 bf0, bf1;
    #pragma unroll
    for (int j = 0; j < 8; ++j) {
        bf0[j] = (_Float16)emb[ucol * 16 + 8 * h + j];
        bf1[j] = (_Float16)emb[(ucol + 32) * 16 + 8 * h + j];
    }
    f32x16 zacc;
    #pragma unroll
    for (int i = 0; i < 16; ++i) zacc[i] = 0.f;

    for (int j = 0; j < GNPB; j += 16) {
        const int nlA = wv + j;
        const int nlB = wv + j + 8;
        const int sA = lstart[nlA], cA = hist[nlA];
        const int sB = lstart[nlB], cB = hist[nlB];
        const int cmax = (cA > cB) ? cA : cB;
        float r0A = 0.f, r1A = 0.f, r0B = 0.f, r1B = 0.f;
        for (int ch = 0; ch < cmax; ch += 32) {
            bool vA = (ch + ucol) < cA;
            bool vB = (ch + ucol) < cB;
            u64 recA = lraw[perm[vA ? (sA + ch + ucol) : 0]];
            u64 recB = lraw[perm[vB ? (sB + ch + ucol) : 0]];
            float wA = vA ? __uint_as_float((uint)(recA >> 32)) : 0.f;
            float wB = vB ? __uint_as_float((uint)(recB >> 32)) : 0.f;
            int eA = (int)((uint)recA & 0x3FFFFFu);
            int eB = (int)((uint)recB & 0x3FFFFFu);
            // all 4 random-line loads issued before any MFMA
            f32x4 a0 = cf4[(size_t)eA * 4 + 2 * h];
            f32x4 a1 = cf4[(size_t)eA * 4 + 2 * h + 1];
            f32x4 b0 = cf4[(size_t)eB * 4 + 2 * h];
            f32x4 b1 = cf4[(size_t)eB * 4 + 2 * h + 1];
            {   // node A: sequential MFMA+reduce, one f32x16 live
                f16x8 fa;
                fa[0] = (_Float16)(a0.x * wA); fa[1] = (_Float16)(a0.y * wA);
                fa[2] = (_Float16)(a0.z * wA); fa[3] = (_Float16)(a0.w * wA);
                fa[4] = (_Float16)(a1.x * wA); fa[5] = (_Float16)(a1.y * wA);
                fa[6] = (_Float16)(a1.z * wA); fa[7] = (_Float16)(a1.w * wA);
                {
                    f32x16 d0 = __builtin_amdgcn_mfma_f32_32x32x16_f16(fa, bf0, zacc, 0, 0, 0);
                    float t = 0.f;
                    #pragma unroll
                    for (int r2 = 0; r2 < 16; ++r2) t += fmaxf(d0[r2], 0.f);
                    r0A += t;
                }
                {
                    f32x16 d1 = __builtin_amdgcn_mfma_f32_32x32x16_f16(fa, bf1, zacc, 0, 0, 0);
                    float t = 0.f;
                    #pragma unroll
                    for (int r2 = 0; r2 < 16; ++r2) t += fmaxf(d1[r2], 0.f);
                    r1A += t;
                }
            }
            {   // node B
                f16x8 fb;
                fb[0] = (_Float16)(b0.x * wB); fb[1] = (_Float16)(b0.y * wB);
                fb[2] = (_Float16)(b0.z * wB); fb[3] = (_Float16)(b0.w * wB);
                fb[4] = (_Float16)(b1.x * wB); fb[5] = (_Float16)(b1.y * wB);
                fb[6] = (_Float16)(b1.z * wB); fb[7] = (_Float16)(b1.w * wB);
                {
                    f32x16 d0 = __builtin_amdgcn_mfma_f32_32x32x16_f16(fb, bf0, zacc, 0, 0, 0);
                    float t = 0.f;
                    #pragma unroll
                    for (int r2 = 0; r2 < 16; ++r2) t += fmaxf(d0[r2], 0.f);
                    r0B += t;
                }
                {
                    f32x16 d1 = __builtin_amdgcn_mfma_f32_32x32x16_f16(fb, bf1, zacc, 0, 0, 0);
                    float t = 0.f;
                    #pragma unroll
                    for (int r2 = 0; r2 < 16; ++r2) t += fmaxf(d1[r2], 0.f);
                    r1B += t;
                }
            }
        }
        r0A += __shfl_xor(r0A, 32); r1A += __shfl_xor(r1A, 32);
        r0B += __shfl_xor(r0B, 32); r1B += __shfl_xor(r1B, 32);
        int nodeA = r * NPB + nlA;
        int nodeB = r * NPB + nlB;
        if (nodeA < NODES)
            out[(size_t)nodeA * 64 + l] = (h ? r1A : r0A) / lden[nlA];
        if (nodeB < NODES)
            out[(size_t)nodeB * 64 + l] = (h ? r1B : r0B) / lden[nlB];
    }
}

// ================= guarded fallbacks (no-op when flag==0 / null) =================

__global__ __launch_bounds__(256) void zero_fb(
    float* __restrict__ out, float* __restrict__ den, int nout,
    const int* __restrict__ flag)
{
    if (flag && !*flag) return;
    int i = blockIdx.x * blockDim.x + threadIdx.x;
    int stride = gridDim.x * blockDim.x;
    for (int j = i; j < nout; j += stride) out[j] = 0.f;
    for (int j = i; j < NODES; j += stride) den[j] = 0.f;
}

__global__ __launch_bounds__(256) void edge_scatter_fb(
    const float* __restrict__ emb, const float* __restrict__ cf,
    const float* __restrict__ wts, const int* __restrict__ idx,
    float* __restrict__ num, float* __restrict__ den, int E,
    const int* __restrict__ flag)
{
    if (flag && !*flag) return;
    const int lane = threadIdx.x & 63;
    float er[16];
    #pragma unroll
    for (int f = 0; f < 16; ++f) er[f] = emb[lane * 16 + f];
    int wid = rfl_i((int)((blockIdx.x * blockDim.x + threadIdx.x) >> 6));
    int nw = (gridDim.x * blockDim.x) >> 6;
    for (int e = wid; e < E; e += nw) {
        const float* c = cf + (size_t)e * 16;
        float a = 0.f;
        #pragma unroll
        for (int f = 0; f < 16; ++f) a = fmaf(c[f], er[f], a);
        float wv = wts[e];
        int n = idx[e];
        unsafeAtomicAdd(num + (size_t)n * 64 + lane, fmaxf(a, 0.f) * wv);
        if (lane == 0) unsafeAtomicAdd(den + n, wv);
    }
}

__global__ __launch_bounds__(256) void divide_fb(
    float* __restrict__ out, const float* __restrict__ den, int nvec,
    const int* __restrict__ flag)
{
    if (flag && !*flag) return;
    int i = blockIdx.x * blockDim.x + threadIdx.x;
    int stride = gridDim.x * blockDim.x;
    float4* o4 = reinterpret_cast<float4*>(out);
    for (; i < nvec; i += stride) {
        float4 v = o4[i];
        float d = den[i >> 4];
        v.x /= d; v.y /= d; v.z /= d; v.w /= d;
        o4[i] = v;
    }
}

extern "C" void kernel_launch(void* const* d_in, const int* in_sizes, int n_in,
                              void* d_out, int out_size, void* d_ws, size_t ws_size,
                              hipStream_t stream)
{
    const float* emb = (const float*)d_in[0];   // (64,16)
    const float* cf  = (const float*)d_in[1];   // (E,16)
    const float* wts = (const float*)d_in[2];   // (E,)
    const int*   idx = (const int*)d_in[3];     // (E,)
    int E = in_sizes[2];
    float* out = (float*)d_out;

    // ws layout (~52 MB)
    char* p = (char*)d_ws;
    auto take = [&](size_t bytes) { char* r = p; p += (bytes + 255) & ~(size_t)255; return r; };
    int*  gcur = (int*)take((size_t)NBUCK * 32 * sizeof(int));    // 200 KB padded
    float* den = (float*)take((size_t)NODES * sizeof(float));     // fallback only
    int*  flag = (int*)take(256);
    u64*  recs = (u64*)take((size_t)NBUCK * RCAP * sizeof(u64));  // 51 MB fixed regions
    size_t need = (size_t)(p - (char*)d_ws);

    if (E < (1 << 22) && ws_size >= need) {
        (void)hipMemsetAsync(gcur, 0, (size_t)NBUCK * 32 * sizeof(int), stream);
        (void)hipMemsetAsync(flag, 0, sizeof(int), stream);
        scatter_bin<<<SGRID, 256, 0, stream>>>(idx, wts, gcur, recs, flag, E);
        sort_gather<<<NBUCK, 512, 0, stream>>>(
            emb, (const f32x4*)cf, gcur, recs, out, flag);
        // guarded fallback chain (no-ops when flag==0)
        zero_fb<<<2048, 256, 0, stream>>>(out, den, out_size, flag);
        edge_scatter_fb<<<4096, 256, 0, stream>>>(emb, cf, wts, idx, out, den, E, flag);
        divide_fb<<<2048, 256, 0, stream>>>(out, den, out_size / 4, flag);
    } else {
        // host fallback: plain atomic scatter (needs only NODES floats of ws)
        float* den2 = (float*)d_ws;
        (void)hipMemsetAsync(d_out, 0, (size_t)out_size * sizeof(float), stream);
        (void)hipMemsetAsync(d_ws, 0, (size_t)NODES * sizeof(float), stream);
        edge_scatter_fb<<<4096, 256, 0, stream>>>(emb, cf, wts, idx, out, den2, E, nullptr);
        divide_fb<<<2048, 256, 0, stream>>>(out, den2, out_size / 4, nullptr);
    }
}